// Round 8
// baseline (506.290 us; speedup 1.0000x reference)
//
#include <hip/hip_runtime.h>

#define N_NODES 50000
#define N_EDGES 600000
#define DIM 128
#define NGRAPH 128
#define NLAYER 4
#define BN_EPS 1e-5f
#define SCAN_BLK 1024

#define EN_BLOCKS 3125    // N/16 nodes per block
#define WT_BLOCKS 512     // 2*L*D*D/256
#define HB_BLOCKS 2344    // ceil(E/256)

using short8  = __attribute__((ext_vector_type(8))) short;
using float4v = __attribute__((ext_vector_type(4))) float;

__device__ __forceinline__ float bf2f(unsigned short u) {
    union { unsigned int i; float f; } c; c.i = ((unsigned int)u) << 16; return c.f;
}
__device__ __forceinline__ unsigned short f2bf(float f) {
    union { float f; unsigned int i; } c; c.f = f;
    unsigned int x = c.i;
    return (unsigned short)((x + 0x7fffu + ((x >> 16) & 1u)) >> 16);
}

// ---------------- fused pre-pass: encode | weight-transpose | degree-histogram ----------------
__global__ void fused_pre_kernel(const int* __restrict__ feat_id,
                                 const float* __restrict__ rwse,
                                 const int* __restrict__ indeg,
                                 const float* __restrict__ value_W,
                                 const float* __restrict__ value_b,
                                 const float* __restrict__ rwse_W,
                                 const float* __restrict__ rwse_b,
                                 const float* __restrict__ deg_emb,
                                 unsigned short* __restrict__ hout,
                                 const float* __restrict__ W1,
                                 const float* __restrict__ W2,
                                 unsigned short* __restrict__ w1t,
                                 unsigned short* __restrict__ w2t,
                                 const int* __restrict__ dst,
                                 int* __restrict__ cnt)
{
    int b = blockIdx.x;
    if (b < EN_BLOCKS) {
        __shared__ float srw[16][16];
        __shared__ int   sfid[16], sdeg[16];
        const int t = threadIdx.x;
        const int base = b * 16;
        srw[t >> 4][t & 15] = rwse[(size_t)base * 16 + t];
        if (t < 16) sfid[t] = feat_id[base + t] & 127;
        else if (t < 32) {
            int dg = indeg[base + t - 16];
            sdeg[t - 16] = dg < 0 ? 0 : (dg > 1000 ? 1000 : dg);
        }
        const int d = t & 127, half = t >> 7;
        float wk[16];
#pragma unroll
        for (int k = 0; k < 16; ++k) wk[k] = rwse_W[k * DIM + d];
        float vb = value_b[d] + rwse_b[d];
        __syncthreads();
#pragma unroll
        for (int nn = 0; nn < 8; ++nn) {
            int nl = half * 8 + nn;
            int node = base + nl;
            float v = value_W[sfid[nl] * DIM + d] + vb + deg_emb[sdeg[nl] * DIM + d];
            float acc = 0.f;
#pragma unroll
            for (int k = 0; k < 16; ++k) acc += srw[nl][k] * wk[k];
            hout[(size_t)node * DIM + d] = f2bf(v + acc);
        }
    } else if (b < EN_BLOCKS + WT_BLOCKS) {
        int idx = (b - EN_BLOCKS) * 256 + threadIdx.x;
        int i = idx & (DIM * DIM - 1);
        int l = (idx >> 14) & 3;
        int is2 = idx >= NLAYER * DIM * DIM;
        int n = i >> 7, k = i & 127;
        const float* W = (is2 ? W2 : W1) + l * DIM * DIM;
        unsigned short v = f2bf(W[k * DIM + n]);
        (is2 ? w2t : w1t)[l * DIM * DIM + n * DIM + k] = v;
    } else {
        int e = (b - EN_BLOCKS - WT_BLOCKS) * 256 + threadIdx.x;
        if (e < N_EDGES) atomicAdd(&cnt[dst[e]], 1);
    }
}

// ---------------- CSR build ----------------
__global__ void scanA_kernel(const int* __restrict__ cnt, int* __restrict__ rp, int* __restrict__ bsum) {
    __shared__ int sc[SCAN_BLK];
    int t = threadIdx.x, i = blockIdx.x * SCAN_BLK + t;
    int v = (i < N_NODES) ? cnt[i] : 0;
    sc[t] = v; __syncthreads();
    for (int off = 1; off < SCAN_BLK; off <<= 1) {
        int add = (t >= off) ? sc[t - off] : 0;
        __syncthreads();
        sc[t] += add;
        __syncthreads();
    }
    if (i < N_NODES) rp[i] = sc[t] - v;
    if (t == SCAN_BLK - 1) bsum[blockIdx.x] = sc[t];
}

__global__ void scan_fixup_kernel(int* __restrict__ rp, const int* __restrict__ bsum,
                                  int* __restrict__ cur, int nsb) {
    __shared__ int sbx[64];
    int t = threadIdx.x;
    if (t < 64) {
        int v = (t < nsb) ? bsum[t] : 0;
        int orig = v;
        for (int off = 1; off < 64; off <<= 1) {
            int y = __shfl_up(v, off, 64);
            if (t >= off) v += y;
        }
        sbx[t] = v - orig;
    }
    __syncthreads();
    int i = blockIdx.x * 256 + t;
    if (i < N_NODES) { int v = rp[i] + sbx[i >> 10]; rp[i] = v; cur[i] = v; }
    else if (i == N_NODES) rp[i] = N_EDGES;
}

__global__ void scatter_kernel(const int* __restrict__ src, const int* __restrict__ dst,
                               int* __restrict__ cur, int* __restrict__ esrc) {
    int e = blockIdx.x * blockDim.x + threadIdx.x;
    if (e < N_EDGES) {
        int pos = atomicAdd(&cur[dst[e]], 1);
        esrc[pos] = src[e];
    }
}

// ---------------- fused layer: GIN gather + MLP + BN + ReLU, one kernel per layer ----------------
// Block = 4 waves x 64 nodes; each wave owns 16 rows end-to-end, zero barriers.
// LDS sA[64][128] bf16 partitioned per wave (rows wave*16..+15), XOR-swizzled.
__global__ void __launch_bounds__(256, 4) layer_kernel(
    const unsigned short* __restrict__ hin,
    const int* __restrict__ rp,
    const int* __restrict__ esrc,
    const unsigned short* __restrict__ w1t,
    const unsigned short* __restrict__ w2t,
    const float* __restrict__ b1, const float* __restrict__ b2,
    const float* __restrict__ gam, const float* __restrict__ bet,
    const float* __restrict__ mean, const float* __restrict__ var,
    unsigned short* __restrict__ hout, float* __restrict__ fout, int last)
{
    __shared__ unsigned short sA[64 * DIM];   // 16 KB
    const int tid = threadIdx.x;
    const int wave = tid >> 6, lane = tid & 63;
    const int fr = lane & 15, fg = lane >> 4;
    const int grp = fg, q = fr;               // gather decomposition (same lanes)
    const int wrow0 = wave * 16;
    const int rowbase = blockIdx.x * 64 + wrow0;   // this wave's first node

    // ---- gather phase: agg = h[node] + sum_{src->node} h[src], straight into LDS ----
    for (int j = 0; j < 16; ++j) {
        int node = rowbase + j;
        float a[8];
#pragma unroll
        for (int i = 0; i < 8; ++i) a[i] = 0.f;
        if (node < N_NODES) {
            if (grp == 0) {
                uint4 s = *(const uint4*)(hin + (size_t)node * DIM + q * 8);
                a[0] = bf2f((unsigned short)(s.x & 0xffff)); a[1] = bf2f((unsigned short)(s.x >> 16));
                a[2] = bf2f((unsigned short)(s.y & 0xffff)); a[3] = bf2f((unsigned short)(s.y >> 16));
                a[4] = bf2f((unsigned short)(s.z & 0xffff)); a[5] = bf2f((unsigned short)(s.z >> 16));
                a[6] = bf2f((unsigned short)(s.w & 0xffff)); a[7] = bf2f((unsigned short)(s.w >> 16));
            }
            int e1 = rp[node + 1];
            int e = rp[node] + grp;
            int snext = (e < e1) ? esrc[e] : 0;
            while (e < e1) {
                int s = snext;
                int en = e + 4;
                snext = (en < e1) ? esrc[en] : 0;
                uint4 v = *(const uint4*)(hin + (size_t)s * DIM + q * 8);
                a[0] += bf2f((unsigned short)(v.x & 0xffff)); a[1] += bf2f((unsigned short)(v.x >> 16));
                a[2] += bf2f((unsigned short)(v.y & 0xffff)); a[3] += bf2f((unsigned short)(v.y >> 16));
                a[4] += bf2f((unsigned short)(v.z & 0xffff)); a[5] += bf2f((unsigned short)(v.z >> 16));
                a[6] += bf2f((unsigned short)(v.w & 0xffff)); a[7] += bf2f((unsigned short)(v.w >> 16));
                e = en;
            }
        }
#pragma unroll
        for (int i = 0; i < 8; ++i) {
            a[i] += __shfl_xor(a[i], 16, 64);
            a[i] += __shfl_xor(a[i], 32, 64);
        }
        if (grp == 0) {
            uint4 o;
            o.x = (unsigned int)f2bf(a[0]) | ((unsigned int)f2bf(a[1]) << 16);
            o.y = (unsigned int)f2bf(a[2]) | ((unsigned int)f2bf(a[3]) << 16);
            o.z = (unsigned int)f2bf(a[4]) | ((unsigned int)f2bf(a[5]) << 16);
            o.w = (unsigned int)f2bf(a[6]) | ((unsigned int)f2bf(a[7]) << 16);
            int row = wrow0 + j;
            int byte = row * 256 + q * 16; byte ^= (row & 7) << 4;
            *(uint4*)((char*)sA + byte) = o;
        }
    }
    // no barrier: each wave reads/writes only its own 16 LDS rows

    // ---- GEMM1: A from sA (own rows), B direct from w1t (L1-hot) ----
    short8 a0, a1, a2, a3;
    {
        int row = wrow0 + fr;
        int sw = (row & 7) << 4;
        a0 = *(const short8*)((char*)sA + ((row * 256 + (0  + fg * 8) * 2) ^ sw));
        a1 = *(const short8*)((char*)sA + ((row * 256 + (32 + fg * 8) * 2) ^ sw));
        a2 = *(const short8*)((char*)sA + ((row * 256 + (64 + fg * 8) * 2) ^ sw));
        a3 = *(const short8*)((char*)sA + ((row * 256 + (96 + fg * 8) * 2) ^ sw));
    }

    float4v acc[8];
#pragma unroll
    for (int n = 0; n < 8; ++n) acc[n] = (float4v){0.f, 0.f, 0.f, 0.f};

    const unsigned short* bp1 = w1t + fr * DIM + fg * 8;
#pragma unroll
    for (int nb = 0; nb < 8; ++nb) {
        const unsigned short* bb = bp1 + nb * 16 * DIM;
        short8 b0 = *(const short8*)(bb);
        short8 b1v = *(const short8*)(bb + 32);
        short8 b2v = *(const short8*)(bb + 64);
        short8 b3v = *(const short8*)(bb + 96);
        acc[nb] = __builtin_amdgcn_mfma_f32_16x16x32_bf16(a0, b0, acc[nb], 0, 0, 0);
        acc[nb] = __builtin_amdgcn_mfma_f32_16x16x32_bf16(a1, b1v, acc[nb], 0, 0, 0);
        acc[nb] = __builtin_amdgcn_mfma_f32_16x16x32_bf16(a2, b2v, acc[nb], 0, 0, 0);
        acc[nb] = __builtin_amdgcn_mfma_f32_16x16x32_bf16(a3, b3v, acc[nb], 0, 0, 0);
    }

    // ---- mid: bias + relu -> bf16 back into own sA rows (C-layout row = fg*4+r) ----
#pragma unroll
    for (int nb = 0; nb < 8; ++nb) {
        int col = nb * 16 + fr;
        float bias = b1[col];
#pragma unroll
        for (int r = 0; r < 4; ++r) {
            int row = wrow0 + fg * 4 + r;
            float v = acc[nb][r] + bias;
            v = fmaxf(v, 0.f);
            int byte = row * 256 + col * 2; byte ^= (row & 7) << 4;
            *(unsigned short*)((char*)sA + byte) = f2bf(v);
        }
    }
    // same-wave LDS ordering: reads below see the writes above without a barrier

    // ---- GEMM2: A from sA (own rows), B direct from w2t ----
    short8 m0, m1, m2, m3;
    {
        int row = wrow0 + fr;
        int sw = (row & 7) << 4;
        m0 = *(const short8*)((char*)sA + ((row * 256 + (0  + fg * 8) * 2) ^ sw));
        m1 = *(const short8*)((char*)sA + ((row * 256 + (32 + fg * 8) * 2) ^ sw));
        m2 = *(const short8*)((char*)sA + ((row * 256 + (64 + fg * 8) * 2) ^ sw));
        m3 = *(const short8*)((char*)sA + ((row * 256 + (96 + fg * 8) * 2) ^ sw));
    }

    float4v acc2[8];
#pragma unroll
    for (int n = 0; n < 8; ++n) acc2[n] = (float4v){0.f, 0.f, 0.f, 0.f};

    const unsigned short* bp2 = w2t + fr * DIM + fg * 8;
#pragma unroll
    for (int nb = 0; nb < 8; ++nb) {
        const unsigned short* bb = bp2 + nb * 16 * DIM;
        short8 b0 = *(const short8*)(bb);
        short8 b1v = *(const short8*)(bb + 32);
        short8 b2v = *(const short8*)(bb + 64);
        short8 b3v = *(const short8*)(bb + 96);
        acc2[nb] = __builtin_amdgcn_mfma_f32_16x16x32_bf16(m0, b0, acc2[nb], 0, 0, 0);
        acc2[nb] = __builtin_amdgcn_mfma_f32_16x16x32_bf16(m1, b1v, acc2[nb], 0, 0, 0);
        acc2[nb] = __builtin_amdgcn_mfma_f32_16x16x32_bf16(m2, b2v, acc2[nb], 0, 0, 0);
        acc2[nb] = __builtin_amdgcn_mfma_f32_16x16x32_bf16(m3, b3v, acc2[nb], 0, 0, 0);
    }

    // ---- epilogue: +b2, BN, ReLU, store ----
#pragma unroll
    for (int nb = 0; nb < 8; ++nb) {
        int col = nb * 16 + fr;
        float bias = b2[col];
        float iv = gam[col] * rsqrtf(var[col] + BN_EPS);
        float mn = mean[col], bt = bet[col];
#pragma unroll
        for (int r = 0; r < 4; ++r) {
            int node = rowbase + fg * 4 + r;
            if (node < N_NODES) {
                float v = acc2[nb][r] + bias;
                v = (v - mn) * iv + bt;
                v = fmaxf(v, 0.f);
                if (last) fout[(size_t)node * DIM + col] = v;
                else hout[(size_t)node * DIM + col] = f2bf(v);
            }
        }
    }
}

// ---------------- pooling: 8 blocks/graph non-atomic partials, then combine+divide ----------------
__global__ void __launch_bounds__(256) pool_partial_kernel(const float* __restrict__ h,
                                                           const int* __restrict__ batch,
                                                           float* __restrict__ partial)
{
    __shared__ float sums[256];
    __shared__ int sb[2];
    int g = blockIdx.x >> 3, split = blockIdx.x & 7;
    if (threadIdx.x < 2) {
        int target = g + threadIdx.x;
        int lo = 0, hi = N_NODES;
        while (lo < hi) { int mid = (lo + hi) >> 1; if (batch[mid] < target) lo = mid + 1; else hi = mid; }
        sb[threadIdx.x] = lo;
    }
    __syncthreads();
    int lo = sb[0], hi = sb[1];
    int d = threadIdx.x & 127, half = threadIdx.x >> 7;
    float acc = 0.f;
    for (int n = lo + split * 2 + half; n < hi; n += 16) acc += h[(size_t)n * DIM + d];
    sums[threadIdx.x] = acc;
    __syncthreads();
    if (threadIdx.x < 128)
        partial[blockIdx.x * DIM + threadIdx.x] = sums[threadIdx.x] + sums[threadIdx.x + 128];
}

__global__ void pool_comb_kernel(const float* __restrict__ partial,
                                 const int* __restrict__ batch,
                                 float* __restrict__ out)
{
    __shared__ int sb[2];
    int g = blockIdx.x, t = threadIdx.x;
    if (t < 2) {
        int target = g + t;
        int lo = 0, hi = N_NODES;
        while (lo < hi) { int mid = (lo + hi) >> 1; if (batch[mid] < target) lo = mid + 1; else hi = mid; }
        sb[t] = lo;
    }
    __syncthreads();
    float s = 0.f;
#pragma unroll
    for (int sp = 0; sp < 8; ++sp) s += partial[(g * 8 + sp) * DIM + t];
    float c = (float)(sb[1] - sb[0]);
    out[g * DIM + t] = s / fmaxf(c, 1.f);
}

extern "C" void kernel_launch(void* const* d_in, const int* in_sizes, int n_in,
                              void* d_out, int out_size, void* d_ws, size_t ws_size,
                              hipStream_t stream)
{
    const int*   feat_id = (const int*)d_in[0];
    const int*   eidx    = (const int*)d_in[1];
    const int*   batch   = (const int*)d_in[2];
    const float* rwse    = (const float*)d_in[3];
    const int*   indeg   = (const int*)d_in[4];
    const float* value_W = (const float*)d_in[5];
    const float* value_b = (const float*)d_in[6];
    const float* rwse_W  = (const float*)d_in[7];
    const float* rwse_b  = (const float*)d_in[8];
    const float* deg_emb = (const float*)d_in[9];
    const float* W1      = (const float*)d_in[10];
    const float* b1      = (const float*)d_in[11];
    const float* W2      = (const float*)d_in[12];
    const float* b2      = (const float*)d_in[13];
    const float* gam     = (const float*)d_in[14];
    const float* bet     = (const float*)d_in[15];
    const float* mean    = (const float*)d_in[16];
    const float* var     = (const float*)d_in[17];

    const int* srcv = eidx;
    const int* dstv = eidx + N_EDGES;

    char* p = (char*)d_ws;
    auto alloc = [&](size_t bytes) { char* r = p; p += (bytes + 255) & ~(size_t)255; return r; };
    unsigned short* hA   = (unsigned short*)alloc((size_t)N_NODES * DIM * 2);
    unsigned short* hB   = (unsigned short*)alloc((size_t)N_NODES * DIM * 2);
    int* cnt  = (int*)alloc((size_t)N_NODES * 4);
    int* rp   = (int*)alloc((size_t)(N_NODES + 1) * 4);
    int* cur  = (int*)alloc((size_t)N_NODES * 4);
    int* bsum = (int*)alloc(64 * 4);
    int* esrc = (int*)alloc((size_t)N_EDGES * 4);
    unsigned short* w1t = (unsigned short*)alloc((size_t)NLAYER * DIM * DIM * 2);
    unsigned short* w2t = (unsigned short*)alloc((size_t)NLAYER * DIM * DIM * 2);
    float* partial = (float*)alloc((size_t)NGRAPH * 8 * DIM * 4);

    float* out = (float*)d_out;
    float* hf  = out + NGRAPH * DIM;   // h output region [N, D] f32

    hipMemsetAsync(cnt, 0, (size_t)N_NODES * 4, stream);
    fused_pre_kernel<<<EN_BLOCKS + WT_BLOCKS + HB_BLOCKS, 256, 0, stream>>>(
        feat_id, rwse, indeg, value_W, value_b, rwse_W, rwse_b, deg_emb, hA,
        W1, W2, w1t, w2t, dstv, cnt);
    int nsb = (N_NODES + SCAN_BLK - 1) / SCAN_BLK;   // 49
    scanA_kernel<<<nsb, SCAN_BLK, 0, stream>>>(cnt, rp, bsum);
    scan_fixup_kernel<<<(N_NODES + 1 + 255) / 256, 256, 0, stream>>>(rp, bsum, cur, nsb);
    scatter_kernel<<<(N_EDGES + 255) / 256, 256, 0, stream>>>(srcv, dstv, cur, esrc);

    const int nlb = (N_NODES + 63) / 64;   // 782
    for (int l = 0; l < NLAYER; ++l) {
        const unsigned short* hi = (l & 1) ? hB : hA;
        unsigned short*       ho = (l & 1) ? hA : hB;
        layer_kernel<<<nlb, 256, 0, stream>>>(hi, rp, esrc,
            w1t + l * DIM * DIM, w2t + l * DIM * DIM,
            b1 + l * DIM, b2 + l * DIM, gam + l * DIM, bet + l * DIM,
            mean + l * DIM, var + l * DIM,
            ho, hf, (l == NLAYER - 1) ? 1 : 0);
    }
    pool_partial_kernel<<<NGRAPH * 8, 256, 0, stream>>>(hf, batch, partial);
    pool_comb_kernel<<<NGRAPH, DIM, 0, stream>>>(partial, batch, out);
}

// Round 9
// 399.781 us; speedup vs baseline: 1.2664x; 1.2664x over previous
//
#include <hip/hip_runtime.h>

#define N_NODES 50000
#define N_EDGES 600000
#define DIM 128
#define NGRAPH 128
#define NLAYER 4
#define BN_EPS 1e-5f
#define SCAN_BLK 1024

#define EN_BLOCKS 3125    // N/16 nodes per block
#define WT_BLOCKS 512     // 2*L*D*D/256
#define HB_BLOCKS 2344    // ceil(E/256)

using short8  = __attribute__((ext_vector_type(8))) short;
using float4v = __attribute__((ext_vector_type(4))) float;

__device__ __forceinline__ float bf2f(unsigned short u) {
    union { unsigned int i; float f; } c; c.i = ((unsigned int)u) << 16; return c.f;
}
__device__ __forceinline__ unsigned short f2bf(float f) {
    union { float f; unsigned int i; } c; c.f = f;
    unsigned int x = c.i;
    return (unsigned short)((x + 0x7fffu + ((x >> 16) & 1u)) >> 16);
}

// ---------------- fused pre-pass: encode | weight-transpose | degree-histogram ----------------
__global__ void fused_pre_kernel(const int* __restrict__ feat_id,
                                 const float* __restrict__ rwse,
                                 const int* __restrict__ indeg,
                                 const float* __restrict__ value_W,
                                 const float* __restrict__ value_b,
                                 const float* __restrict__ rwse_W,
                                 const float* __restrict__ rwse_b,
                                 const float* __restrict__ deg_emb,
                                 unsigned short* __restrict__ hout,
                                 const float* __restrict__ W1,
                                 const float* __restrict__ W2,
                                 unsigned short* __restrict__ w1t,
                                 unsigned short* __restrict__ w2t,
                                 const int* __restrict__ dst,
                                 int* __restrict__ cnt)
{
    int b = blockIdx.x;
    if (b < EN_BLOCKS) {
        __shared__ float srw[16][16];
        __shared__ int   sfid[16], sdeg[16];
        const int t = threadIdx.x;
        const int base = b * 16;
        srw[t >> 4][t & 15] = rwse[(size_t)base * 16 + t];
        if (t < 16) sfid[t] = feat_id[base + t] & 127;
        else if (t < 32) {
            int dg = indeg[base + t - 16];
            sdeg[t - 16] = dg < 0 ? 0 : (dg > 1000 ? 1000 : dg);
        }
        const int d = t & 127, half = t >> 7;
        float wk[16];
#pragma unroll
        for (int k = 0; k < 16; ++k) wk[k] = rwse_W[k * DIM + d];
        float vb = value_b[d] + rwse_b[d];
        __syncthreads();
#pragma unroll
        for (int nn = 0; nn < 8; ++nn) {
            int nl = half * 8 + nn;
            int node = base + nl;
            float v = value_W[sfid[nl] * DIM + d] + vb + deg_emb[sdeg[nl] * DIM + d];
            float acc = 0.f;
#pragma unroll
            for (int k = 0; k < 16; ++k) acc += srw[nl][k] * wk[k];
            hout[(size_t)node * DIM + d] = f2bf(v + acc);
        }
    } else if (b < EN_BLOCKS + WT_BLOCKS) {
        int idx = (b - EN_BLOCKS) * 256 + threadIdx.x;
        int i = idx & (DIM * DIM - 1);
        int l = (idx >> 14) & 3;
        int is2 = idx >= NLAYER * DIM * DIM;
        int n = i >> 7, k = i & 127;
        const float* W = (is2 ? W2 : W1) + l * DIM * DIM;
        unsigned short v = f2bf(W[k * DIM + n]);
        (is2 ? w2t : w1t)[l * DIM * DIM + n * DIM + k] = v;
    } else {
        int e = (b - EN_BLOCKS - WT_BLOCKS) * 256 + threadIdx.x;
        if (e < N_EDGES) atomicAdd(&cnt[dst[e]], 1);
    }
}

// ---------------- CSR build ----------------
__global__ void scanA_kernel(const int* __restrict__ cnt, int* __restrict__ rp, int* __restrict__ bsum) {
    __shared__ int sc[SCAN_BLK];
    int t = threadIdx.x, i = blockIdx.x * SCAN_BLK + t;
    int v = (i < N_NODES) ? cnt[i] : 0;
    sc[t] = v; __syncthreads();
    for (int off = 1; off < SCAN_BLK; off <<= 1) {
        int add = (t >= off) ? sc[t - off] : 0;
        __syncthreads();
        sc[t] += add;
        __syncthreads();
    }
    if (i < N_NODES) rp[i] = sc[t] - v;
    if (t == SCAN_BLK - 1) bsum[blockIdx.x] = sc[t];
}

__global__ void scan_fixup_kernel(int* __restrict__ rp, const int* __restrict__ bsum,
                                  int* __restrict__ cur, int nsb) {
    __shared__ int sbx[64];
    int t = threadIdx.x;
    if (t < 64) {
        int v = (t < nsb) ? bsum[t] : 0;
        int orig = v;
        for (int off = 1; off < 64; off <<= 1) {
            int y = __shfl_up(v, off, 64);
            if (t >= off) v += y;
        }
        sbx[t] = v - orig;
    }
    __syncthreads();
    int i = blockIdx.x * 256 + t;
    if (i < N_NODES) { int v = rp[i] + sbx[i >> 10]; rp[i] = v; cur[i] = v; }
    else if (i == N_NODES) rp[i] = N_EDGES;
}

__global__ void scatter_kernel(const int* __restrict__ src, const int* __restrict__ dst,
                               int* __restrict__ cur, int* __restrict__ esrc) {
    int e = blockIdx.x * blockDim.x + threadIdx.x;
    if (e < N_EDGES) {
        int pos = atomicAdd(&cur[dst[e]], 1);
        esrc[pos] = src[e];
    }
}

// ---------------- fused layer v2: 256 threads / 16 nodes, full-TLP gather + cooperative MLP ----
// Gather: wave w gathers nodes base+w*4 .. +3 (wave-per-node structure of the split agg kernel).
// MLP: wave w owns output cols w*32..w*32+31 of the 16-row tile. acc[2] keeps VGPR <= 64 so
// __launch_bounds__(256,8) gives 8 blocks/CU = 32 waves/CU during the latency-bound gather.
__global__ void __launch_bounds__(256, 8) layer_kernel(
    const unsigned short* __restrict__ hin,
    const int* __restrict__ rp,
    const int* __restrict__ esrc,
    const unsigned short* __restrict__ w1t,
    const unsigned short* __restrict__ w2t,
    const float* __restrict__ b1, const float* __restrict__ b2,
    const float* __restrict__ gam, const float* __restrict__ bet,
    const float* __restrict__ mean, const float* __restrict__ var,
    unsigned short* __restrict__ hout, float* __restrict__ fout, int last)
{
    __shared__ unsigned short sA[16 * DIM];   // 4 KB gather/A tile
    __shared__ unsigned short sM[16 * DIM];   // 4 KB mid tile
    const int tid = threadIdx.x;
    const int wave = tid >> 6, lane = tid & 63;
    const int fr = lane & 15, fg = lane >> 4;
    const int base = blockIdx.x * 16;         // grid 3125 * 16 == N exactly, no tail

    // ---- gather: agg = h[node] + sum_{src->node} h[src] -> sA ----
    for (int j = 0; j < 4; ++j) {
        int row = wave * 4 + j;
        int node = __builtin_amdgcn_readfirstlane(base + row);
        float a[8];
#pragma unroll
        for (int i = 0; i < 8; ++i) a[i] = 0.f;
        if (fg == 0) {
            uint4 s = *(const uint4*)(hin + (size_t)node * DIM + fr * 8);
            a[0] = bf2f((unsigned short)(s.x & 0xffff)); a[1] = bf2f((unsigned short)(s.x >> 16));
            a[2] = bf2f((unsigned short)(s.y & 0xffff)); a[3] = bf2f((unsigned short)(s.y >> 16));
            a[4] = bf2f((unsigned short)(s.z & 0xffff)); a[5] = bf2f((unsigned short)(s.z >> 16));
            a[6] = bf2f((unsigned short)(s.w & 0xffff)); a[7] = bf2f((unsigned short)(s.w >> 16));
        }
        int e1 = rp[node + 1];
        int e = rp[node] + fg;
        int snext = (e < e1) ? esrc[e] : 0;
        while (e < e1) {
            int s = snext;
            int en = e + 4;
            snext = (en < e1) ? esrc[en] : 0;
            uint4 v = *(const uint4*)(hin + (size_t)s * DIM + fr * 8);
            a[0] += bf2f((unsigned short)(v.x & 0xffff)); a[1] += bf2f((unsigned short)(v.x >> 16));
            a[2] += bf2f((unsigned short)(v.y & 0xffff)); a[3] += bf2f((unsigned short)(v.y >> 16));
            a[4] += bf2f((unsigned short)(v.z & 0xffff)); a[5] += bf2f((unsigned short)(v.z >> 16));
            a[6] += bf2f((unsigned short)(v.w & 0xffff)); a[7] += bf2f((unsigned short)(v.w >> 16));
            e = en;
        }
#pragma unroll
        for (int i = 0; i < 8; ++i) {
            a[i] += __shfl_xor(a[i], 16, 64);
            a[i] += __shfl_xor(a[i], 32, 64);
        }
        if (fg == 0) {
            uint4 o;
            o.x = (unsigned int)f2bf(a[0]) | ((unsigned int)f2bf(a[1]) << 16);
            o.y = (unsigned int)f2bf(a[2]) | ((unsigned int)f2bf(a[3]) << 16);
            o.z = (unsigned int)f2bf(a[4]) | ((unsigned int)f2bf(a[5]) << 16);
            o.w = (unsigned int)f2bf(a[6]) | ((unsigned int)f2bf(a[7]) << 16);
            int byte = row * 256 + fr * 16; byte ^= (row & 7) << 4;
            *(uint4*)((char*)sA + byte) = o;
        }
    }
    __syncthreads();

    // ---- GEMM1: A = sA rows 0..15 (full K), B = w1t cols wave*32..+31 (L1-hot) ----
    short8 a0, a1, a2, a3;
    {
        int sw = (fr & 7) << 4;
        a0 = *(const short8*)((char*)sA + ((fr * 256 + (0  + fg * 8) * 2) ^ sw));
        a1 = *(const short8*)((char*)sA + ((fr * 256 + (32 + fg * 8) * 2) ^ sw));
        a2 = *(const short8*)((char*)sA + ((fr * 256 + (64 + fg * 8) * 2) ^ sw));
        a3 = *(const short8*)((char*)sA + ((fr * 256 + (96 + fg * 8) * 2) ^ sw));
    }

    float4v acc[2];
    acc[0] = (float4v){0.f, 0.f, 0.f, 0.f};
    acc[1] = (float4v){0.f, 0.f, 0.f, 0.f};

    const unsigned short* bp1 = w1t + (wave * 32 + fr) * DIM + fg * 8;
#pragma unroll
    for (int nb = 0; nb < 2; ++nb) {
        const unsigned short* bb = bp1 + nb * 16 * DIM;
        short8 b0 = *(const short8*)(bb);
        short8 b1v = *(const short8*)(bb + 32);
        short8 b2v = *(const short8*)(bb + 64);
        short8 b3v = *(const short8*)(bb + 96);
        acc[nb] = __builtin_amdgcn_mfma_f32_16x16x32_bf16(a0, b0, acc[nb], 0, 0, 0);
        acc[nb] = __builtin_amdgcn_mfma_f32_16x16x32_bf16(a1, b1v, acc[nb], 0, 0, 0);
        acc[nb] = __builtin_amdgcn_mfma_f32_16x16x32_bf16(a2, b2v, acc[nb], 0, 0, 0);
        acc[nb] = __builtin_amdgcn_mfma_f32_16x16x32_bf16(a3, b3v, acc[nb], 0, 0, 0);
    }

    // ---- mid: bias + relu -> bf16 into sM (wave's 32-col slice) ----
#pragma unroll
    for (int nb = 0; nb < 2; ++nb) {
        int col = wave * 32 + nb * 16 + fr;
        float bias = b1[col];
#pragma unroll
        for (int r = 0; r < 4; ++r) {
            int row = fg * 4 + r;
            float v = acc[nb][r] + bias;
            v = fmaxf(v, 0.f);
            int byte = row * 256 + col * 2; byte ^= (row & 7) << 4;
            *(unsigned short*)((char*)sM + byte) = f2bf(v);
        }
    }
    __syncthreads();

    // ---- GEMM2: A = sM rows 0..15 (full K), B = w2t cols wave*32..+31 ----
    short8 m0, m1, m2, m3;
    {
        int sw = (fr & 7) << 4;
        m0 = *(const short8*)((char*)sM + ((fr * 256 + (0  + fg * 8) * 2) ^ sw));
        m1 = *(const short8*)((char*)sM + ((fr * 256 + (32 + fg * 8) * 2) ^ sw));
        m2 = *(const short8*)((char*)sM + ((fr * 256 + (64 + fg * 8) * 2) ^ sw));
        m3 = *(const short8*)((char*)sM + ((fr * 256 + (96 + fg * 8) * 2) ^ sw));
    }

    float4v acc2[2];
    acc2[0] = (float4v){0.f, 0.f, 0.f, 0.f};
    acc2[1] = (float4v){0.f, 0.f, 0.f, 0.f};

    const unsigned short* bp2 = w2t + (wave * 32 + fr) * DIM + fg * 8;
#pragma unroll
    for (int nb = 0; nb < 2; ++nb) {
        const unsigned short* bb = bp2 + nb * 16 * DIM;
        short8 b0 = *(const short8*)(bb);
        short8 b1v = *(const short8*)(bb + 32);
        short8 b2v = *(const short8*)(bb + 64);
        short8 b3v = *(const short8*)(bb + 96);
        acc2[nb] = __builtin_amdgcn_mfma_f32_16x16x32_bf16(m0, b0, acc2[nb], 0, 0, 0);
        acc2[nb] = __builtin_amdgcn_mfma_f32_16x16x32_bf16(m1, b1v, acc2[nb], 0, 0, 0);
        acc2[nb] = __builtin_amdgcn_mfma_f32_16x16x32_bf16(m2, b2v, acc2[nb], 0, 0, 0);
        acc2[nb] = __builtin_amdgcn_mfma_f32_16x16x32_bf16(m3, b3v, acc2[nb], 0, 0, 0);
    }

    // ---- epilogue: +b2, BN, ReLU, store ----
#pragma unroll
    for (int nb = 0; nb < 2; ++nb) {
        int col = wave * 32 + nb * 16 + fr;
        float bias = b2[col];
        float iv = gam[col] * rsqrtf(var[col] + BN_EPS);
        float mn = mean[col], bt = bet[col];
#pragma unroll
        for (int r = 0; r < 4; ++r) {
            int node = base + fg * 4 + r;
            float v = acc2[nb][r] + bias;
            v = (v - mn) * iv + bt;
            v = fmaxf(v, 0.f);
            if (last) fout[(size_t)node * DIM + col] = v;
            else hout[(size_t)node * DIM + col] = f2bf(v);
        }
    }
}

// ---------------- pooling: 8 blocks/graph non-atomic partials, then combine+divide ----------------
__global__ void __launch_bounds__(256) pool_partial_kernel(const float* __restrict__ h,
                                                           const int* __restrict__ batch,
                                                           float* __restrict__ partial)
{
    __shared__ float sums[256];
    __shared__ int sb[2];
    int g = blockIdx.x >> 3, split = blockIdx.x & 7;
    if (threadIdx.x < 2) {
        int target = g + threadIdx.x;
        int lo = 0, hi = N_NODES;
        while (lo < hi) { int mid = (lo + hi) >> 1; if (batch[mid] < target) lo = mid + 1; else hi = mid; }
        sb[threadIdx.x] = lo;
    }
    __syncthreads();
    int lo = sb[0], hi = sb[1];
    int d = threadIdx.x & 127, half = threadIdx.x >> 7;
    float acc = 0.f;
    for (int n = lo + split * 2 + half; n < hi; n += 16) acc += h[(size_t)n * DIM + d];
    sums[threadIdx.x] = acc;
    __syncthreads();
    if (threadIdx.x < 128)
        partial[blockIdx.x * DIM + threadIdx.x] = sums[threadIdx.x] + sums[threadIdx.x + 128];
}

__global__ void pool_comb_kernel(const float* __restrict__ partial,
                                 const int* __restrict__ batch,
                                 float* __restrict__ out)
{
    __shared__ int sb[2];
    int g = blockIdx.x, t = threadIdx.x;
    if (t < 2) {
        int target = g + t;
        int lo = 0, hi = N_NODES;
        while (lo < hi) { int mid = (lo + hi) >> 1; if (batch[mid] < target) lo = mid + 1; else hi = mid; }
        sb[t] = lo;
    }
    __syncthreads();
    float s = 0.f;
#pragma unroll
    for (int sp = 0; sp < 8; ++sp) s += partial[(g * 8 + sp) * DIM + t];
    float c = (float)(sb[1] - sb[0]);
    out[g * DIM + t] = s / fmaxf(c, 1.f);
}

extern "C" void kernel_launch(void* const* d_in, const int* in_sizes, int n_in,
                              void* d_out, int out_size, void* d_ws, size_t ws_size,
                              hipStream_t stream)
{
    const int*   feat_id = (const int*)d_in[0];
    const int*   eidx    = (const int*)d_in[1];
    const int*   batch   = (const int*)d_in[2];
    const float* rwse    = (const float*)d_in[3];
    const int*   indeg   = (const int*)d_in[4];
    const float* value_W = (const float*)d_in[5];
    const float* value_b = (const float*)d_in[6];
    const float* rwse_W  = (const float*)d_in[7];
    const float* rwse_b  = (const float*)d_in[8];
    const float* deg_emb = (const float*)d_in[9];
    const float* W1      = (const float*)d_in[10];
    const float* b1      = (const float*)d_in[11];
    const float* W2      = (const float*)d_in[12];
    const float* b2      = (const float*)d_in[13];
    const float* gam     = (const float*)d_in[14];
    const float* bet     = (const float*)d_in[15];
    const float* mean    = (const float*)d_in[16];
    const float* var     = (const float*)d_in[17];

    const int* srcv = eidx;
    const int* dstv = eidx + N_EDGES;

    char* p = (char*)d_ws;
    auto alloc = [&](size_t bytes) { char* r = p; p += (bytes + 255) & ~(size_t)255; return r; };
    unsigned short* hA   = (unsigned short*)alloc((size_t)N_NODES * DIM * 2);
    unsigned short* hB   = (unsigned short*)alloc((size_t)N_NODES * DIM * 2);
    int* cnt  = (int*)alloc((size_t)N_NODES * 4);
    int* rp   = (int*)alloc((size_t)(N_NODES + 1) * 4);
    int* cur  = (int*)alloc((size_t)N_NODES * 4);
    int* bsum = (int*)alloc(64 * 4);
    int* esrc = (int*)alloc((size_t)N_EDGES * 4);
    unsigned short* w1t = (unsigned short*)alloc((size_t)NLAYER * DIM * DIM * 2);
    unsigned short* w2t = (unsigned short*)alloc((size_t)NLAYER * DIM * DIM * 2);
    float* partial = (float*)alloc((size_t)NGRAPH * 8 * DIM * 4);

    float* out = (float*)d_out;
    float* hf  = out + NGRAPH * DIM;   // h output region [N, D] f32

    hipMemsetAsync(cnt, 0, (size_t)N_NODES * 4, stream);
    fused_pre_kernel<<<EN_BLOCKS + WT_BLOCKS + HB_BLOCKS, 256, 0, stream>>>(
        feat_id, rwse, indeg, value_W, value_b, rwse_W, rwse_b, deg_emb, hA,
        W1, W2, w1t, w2t, dstv, cnt);
    int nsb = (N_NODES + SCAN_BLK - 1) / SCAN_BLK;   // 49
    scanA_kernel<<<nsb, SCAN_BLK, 0, stream>>>(cnt, rp, bsum);
    scan_fixup_kernel<<<(N_NODES + 1 + 255) / 256, 256, 0, stream>>>(rp, bsum, cur, nsb);
    scatter_kernel<<<(N_EDGES + 255) / 256, 256, 0, stream>>>(srcv, dstv, cur, esrc);

    const int nlb = N_NODES / 16;   // 3125, exact
    for (int l = 0; l < NLAYER; ++l) {
        const unsigned short* hi = (l & 1) ? hB : hA;
        unsigned short*       ho = (l & 1) ? hA : hB;
        layer_kernel<<<nlb, 256, 0, stream>>>(hi, rp, esrc,
            w1t + l * DIM * DIM, w2t + l * DIM * DIM,
            b1 + l * DIM, b2 + l * DIM, gam + l * DIM, bet + l * DIM,
            mean + l * DIM, var + l * DIM,
            ho, hf, (l == NLAYER - 1) ? 1 : 0);
    }
    pool_partial_kernel<<<NGRAPH * 8, 256, 0, stream>>>(hf, batch, partial);
    pool_comb_kernel<<<NGRAPH, DIM, 0, stream>>>(partial, batch, out);
}

// Round 10
// 381.292 us; speedup vs baseline: 1.3278x; 1.0485x over previous
//
#include <hip/hip_runtime.h>

#define N_NODES 50000
#define N_EDGES 600000
#define DIM 128
#define NGRAPH 128
#define NLAYER 4
#define BN_EPS 1e-5f
#define SCAN_BLK 1024

#define EN_BLOCKS 3125    // N/16 nodes per block
#define WT_BLOCKS 512     // 2*L*D*D/256
#define HB_BLOCKS 2344    // ceil(E/256)

using short8  = __attribute__((ext_vector_type(8))) short;
using float4v = __attribute__((ext_vector_type(4))) float;

__device__ __forceinline__ float bf2f(unsigned short u) {
    union { unsigned int i; float f; } c; c.i = ((unsigned int)u) << 16; return c.f;
}
__device__ __forceinline__ unsigned short f2bf(float f) {
    union { float f; unsigned int i; } c; c.f = f;
    unsigned int x = c.i;
    return (unsigned short)((x + 0x7fffu + ((x >> 16) & 1u)) >> 16);
}

// ---------------- fused pre-pass: encode | weight-transpose | degree-histogram ----------------
__global__ void fused_pre_kernel(const int* __restrict__ feat_id,
                                 const float* __restrict__ rwse,
                                 const int* __restrict__ indeg,
                                 const float* __restrict__ value_W,
                                 const float* __restrict__ value_b,
                                 const float* __restrict__ rwse_W,
                                 const float* __restrict__ rwse_b,
                                 const float* __restrict__ deg_emb,
                                 unsigned short* __restrict__ hout,
                                 const float* __restrict__ W1,
                                 const float* __restrict__ W2,
                                 unsigned short* __restrict__ w1t,
                                 unsigned short* __restrict__ w2t,
                                 const int* __restrict__ dst,
                                 int* __restrict__ cnt)
{
    int b = blockIdx.x;
    if (b < EN_BLOCKS) {
        __shared__ float srw[16][16];
        __shared__ int   sfid[16], sdeg[16];
        const int t = threadIdx.x;
        const int base = b * 16;
        srw[t >> 4][t & 15] = rwse[(size_t)base * 16 + t];
        if (t < 16) sfid[t] = feat_id[base + t] & 127;
        else if (t < 32) {
            int dg = indeg[base + t - 16];
            sdeg[t - 16] = dg < 0 ? 0 : (dg > 1000 ? 1000 : dg);
        }
        const int d = t & 127, half = t >> 7;
        float wk[16];
#pragma unroll
        for (int k = 0; k < 16; ++k) wk[k] = rwse_W[k * DIM + d];
        float vb = value_b[d] + rwse_b[d];
        __syncthreads();
#pragma unroll
        for (int nn = 0; nn < 8; ++nn) {
            int nl = half * 8 + nn;
            int node = base + nl;
            float v = value_W[sfid[nl] * DIM + d] + vb + deg_emb[sdeg[nl] * DIM + d];
            float acc = 0.f;
#pragma unroll
            for (int k = 0; k < 16; ++k) acc += srw[nl][k] * wk[k];
            hout[(size_t)node * DIM + d] = f2bf(v + acc);
        }
    } else if (b < EN_BLOCKS + WT_BLOCKS) {
        int idx = (b - EN_BLOCKS) * 256 + threadIdx.x;
        int i = idx & (DIM * DIM - 1);
        int l = (idx >> 14) & 3;
        int is2 = idx >= NLAYER * DIM * DIM;
        int n = i >> 7, k = i & 127;
        const float* W = (is2 ? W2 : W1) + l * DIM * DIM;
        unsigned short v = f2bf(W[k * DIM + n]);
        (is2 ? w2t : w1t)[l * DIM * DIM + n * DIM + k] = v;
    } else {
        int e = (b - EN_BLOCKS - WT_BLOCKS) * 256 + threadIdx.x;
        if (e < N_EDGES) atomicAdd(&cnt[dst[e]], 1);
    }
}

// ---------------- CSR build ----------------
__global__ void scanA_kernel(const int* __restrict__ cnt, int* __restrict__ rp, int* __restrict__ bsum) {
    __shared__ int sc[SCAN_BLK];
    int t = threadIdx.x, i = blockIdx.x * SCAN_BLK + t;
    int v = (i < N_NODES) ? cnt[i] : 0;
    sc[t] = v; __syncthreads();
    for (int off = 1; off < SCAN_BLK; off <<= 1) {
        int add = (t >= off) ? sc[t - off] : 0;
        __syncthreads();
        sc[t] += add;
        __syncthreads();
    }
    if (i < N_NODES) rp[i] = sc[t] - v;
    if (t == SCAN_BLK - 1) bsum[blockIdx.x] = sc[t];
}

__global__ void scan_fixup_kernel(int* __restrict__ rp, const int* __restrict__ bsum,
                                  int* __restrict__ cur, int nsb) {
    __shared__ int sbx[64];
    int t = threadIdx.x;
    if (t < 64) {
        int v = (t < nsb) ? bsum[t] : 0;
        int orig = v;
        for (int off = 1; off < 64; off <<= 1) {
            int y = __shfl_up(v, off, 64);
            if (t >= off) v += y;
        }
        sbx[t] = v - orig;
    }
    __syncthreads();
    int i = blockIdx.x * 256 + t;
    if (i < N_NODES) { int v = rp[i] + sbx[i >> 10]; rp[i] = v; cur[i] = v; }
    else if (i == N_NODES) rp[i] = N_EDGES;
}

__global__ void scatter_kernel(const int* __restrict__ src, const int* __restrict__ dst,
                               int* __restrict__ cur, int* __restrict__ esrc) {
    int e = blockIdx.x * blockDim.x + threadIdx.x;
    if (e < N_EDGES) {
        int pos = atomicAdd(&cur[dst[e]], 1);
        esrc[pos] = src[e];
    }
}

// ---------------- fused layer v3: de-serialized gather preamble ----------------
// Block = 256 thr / 16 nodes. Gather: wave w owns nodes w*4..w*4+3; rp staged in LDS;
// all 4 first-indices prefetched; self-rows loaded by all 4 groups in parallel (held in regs,
// added after the shfl-reduce by group j). MLP: wave w owns output cols w*32..+31.
__global__ void __launch_bounds__(256, 8) layer_kernel(
    const unsigned short* __restrict__ hin,
    const int* __restrict__ rp,
    const int* __restrict__ esrc,
    const unsigned short* __restrict__ w1t,
    const unsigned short* __restrict__ w2t,
    const float* __restrict__ b1, const float* __restrict__ b2,
    const float* __restrict__ gam, const float* __restrict__ bet,
    const float* __restrict__ mean, const float* __restrict__ var,
    unsigned short* __restrict__ hout, float* __restrict__ fout, int last)
{
    __shared__ unsigned short sA[16 * DIM];   // 4 KB gather/A tile
    __shared__ unsigned short sM[16 * DIM];   // 4 KB mid tile
    __shared__ int sRp[17];
    const int tid = threadIdx.x;
    const int wave = tid >> 6, lane = tid & 63;
    const int fr = lane & 15, fg = lane >> 4;
    const int base = blockIdx.x * 16;         // grid 3125 * 16 == N exactly, no tail

    if (tid < 17) sRp[tid] = rp[base + tid];

    // self-row of node (wave*4+fg), one parallel round across the 4 groups
    const int selfrow = wave * 4 + fg;
    uint4 selfv = *(const uint4*)(hin + (size_t)(base + selfrow) * DIM + fr * 8);

    __syncthreads();   // sRp ready

    // prefetch bounds + first edge index for all 4 nodes (independent loads in flight)
    int e_[4], e1_[4], sfirst_[4];
#pragma unroll
    for (int j = 0; j < 4; ++j) {
        int row = wave * 4 + j;
        e_[j]  = sRp[row] + fg;
        e1_[j] = sRp[row + 1];
        sfirst_[j] = (e_[j] < e1_[j]) ? esrc[e_[j]] : 0;
    }

#pragma unroll
    for (int j = 0; j < 4; ++j) {
        int row = wave * 4 + j;
        float a[8];
#pragma unroll
        for (int i = 0; i < 8; ++i) a[i] = 0.f;
        int e = e_[j], e1v = e1_[j];
        int snext = sfirst_[j];
        while (e < e1v) {
            int s = snext;
            int en = e + 4;
            snext = (en < e1v) ? esrc[en] : 0;
            uint4 v = *(const uint4*)(hin + (size_t)s * DIM + fr * 8);
            a[0] += bf2f((unsigned short)(v.x & 0xffff)); a[1] += bf2f((unsigned short)(v.x >> 16));
            a[2] += bf2f((unsigned short)(v.y & 0xffff)); a[3] += bf2f((unsigned short)(v.y >> 16));
            a[4] += bf2f((unsigned short)(v.z & 0xffff)); a[5] += bf2f((unsigned short)(v.z >> 16));
            a[6] += bf2f((unsigned short)(v.w & 0xffff)); a[7] += bf2f((unsigned short)(v.w >> 16));
            e = en;
        }
#pragma unroll
        for (int i = 0; i < 8; ++i) {
            a[i] += __shfl_xor(a[i], 16, 64);
            a[i] += __shfl_xor(a[i], 32, 64);
        }
        if (fg == j) {   // group j holds node j's self row in regs; all its lanes have the sum
            a[0] += bf2f((unsigned short)(selfv.x & 0xffff)); a[1] += bf2f((unsigned short)(selfv.x >> 16));
            a[2] += bf2f((unsigned short)(selfv.y & 0xffff)); a[3] += bf2f((unsigned short)(selfv.y >> 16));
            a[4] += bf2f((unsigned short)(selfv.z & 0xffff)); a[5] += bf2f((unsigned short)(selfv.z >> 16));
            a[6] += bf2f((unsigned short)(selfv.w & 0xffff)); a[7] += bf2f((unsigned short)(selfv.w >> 16));
            uint4 o;
            o.x = (unsigned int)f2bf(a[0]) | ((unsigned int)f2bf(a[1]) << 16);
            o.y = (unsigned int)f2bf(a[2]) | ((unsigned int)f2bf(a[3]) << 16);
            o.z = (unsigned int)f2bf(a[4]) | ((unsigned int)f2bf(a[5]) << 16);
            o.w = (unsigned int)f2bf(a[6]) | ((unsigned int)f2bf(a[7]) << 16);
            int byte = row * 256 + fr * 16; byte ^= (row & 7) << 4;
            *(uint4*)((char*)sA + byte) = o;
        }
    }
    __syncthreads();

    // ---- GEMM1: A = sA rows 0..15 (full K), B = w1t cols wave*32..+31 (L1-hot) ----
    short8 a0, a1, a2, a3;
    {
        int sw = (fr & 7) << 4;
        a0 = *(const short8*)((char*)sA + ((fr * 256 + (0  + fg * 8) * 2) ^ sw));
        a1 = *(const short8*)((char*)sA + ((fr * 256 + (32 + fg * 8) * 2) ^ sw));
        a2 = *(const short8*)((char*)sA + ((fr * 256 + (64 + fg * 8) * 2) ^ sw));
        a3 = *(const short8*)((char*)sA + ((fr * 256 + (96 + fg * 8) * 2) ^ sw));
    }

    float4v acc[2];
    acc[0] = (float4v){0.f, 0.f, 0.f, 0.f};
    acc[1] = (float4v){0.f, 0.f, 0.f, 0.f};

    const unsigned short* bp1 = w1t + (wave * 32 + fr) * DIM + fg * 8;
#pragma unroll
    for (int nb = 0; nb < 2; ++nb) {
        const unsigned short* bb = bp1 + nb * 16 * DIM;
        short8 b0 = *(const short8*)(bb);
        short8 b1v = *(const short8*)(bb + 32);
        short8 b2v = *(const short8*)(bb + 64);
        short8 b3v = *(const short8*)(bb + 96);
        acc[nb] = __builtin_amdgcn_mfma_f32_16x16x32_bf16(a0, b0, acc[nb], 0, 0, 0);
        acc[nb] = __builtin_amdgcn_mfma_f32_16x16x32_bf16(a1, b1v, acc[nb], 0, 0, 0);
        acc[nb] = __builtin_amdgcn_mfma_f32_16x16x32_bf16(a2, b2v, acc[nb], 0, 0, 0);
        acc[nb] = __builtin_amdgcn_mfma_f32_16x16x32_bf16(a3, b3v, acc[nb], 0, 0, 0);
    }

    // ---- mid: bias + relu -> bf16 into sM (wave's 32-col slice) ----
#pragma unroll
    for (int nb = 0; nb < 2; ++nb) {
        int col = wave * 32 + nb * 16 + fr;
        float bias = b1[col];
#pragma unroll
        for (int r = 0; r < 4; ++r) {
            int row = fg * 4 + r;
            float v = acc[nb][r] + bias;
            v = fmaxf(v, 0.f);
            int byte = row * 256 + col * 2; byte ^= (row & 7) << 4;
            *(unsigned short*)((char*)sM + byte) = f2bf(v);
        }
    }
    __syncthreads();

    // ---- GEMM2: A = sM rows 0..15 (full K), B = w2t cols wave*32..+31 ----
    short8 m0, m1, m2, m3;
    {
        int sw = (fr & 7) << 4;
        m0 = *(const short8*)((char*)sM + ((fr * 256 + (0  + fg * 8) * 2) ^ sw));
        m1 = *(const short8*)((char*)sM + ((fr * 256 + (32 + fg * 8) * 2) ^ sw));
        m2 = *(const short8*)((char*)sM + ((fr * 256 + (64 + fg * 8) * 2) ^ sw));
        m3 = *(const short8*)((char*)sM + ((fr * 256 + (96 + fg * 8) * 2) ^ sw));
    }

    float4v acc2[2];
    acc2[0] = (float4v){0.f, 0.f, 0.f, 0.f};
    acc2[1] = (float4v){0.f, 0.f, 0.f, 0.f};

    const unsigned short* bp2 = w2t + (wave * 32 + fr) * DIM + fg * 8;
#pragma unroll
    for (int nb = 0; nb < 2; ++nb) {
        const unsigned short* bb = bp2 + nb * 16 * DIM;
        short8 b0 = *(const short8*)(bb);
        short8 b1v = *(const short8*)(bb + 32);
        short8 b2v = *(const short8*)(bb + 64);
        short8 b3v = *(const short8*)(bb + 96);
        acc2[nb] = __builtin_amdgcn_mfma_f32_16x16x32_bf16(m0, b0, acc2[nb], 0, 0, 0);
        acc2[nb] = __builtin_amdgcn_mfma_f32_16x16x32_bf16(m1, b1v, acc2[nb], 0, 0, 0);
        acc2[nb] = __builtin_amdgcn_mfma_f32_16x16x32_bf16(m2, b2v, acc2[nb], 0, 0, 0);
        acc2[nb] = __builtin_amdgcn_mfma_f32_16x16x32_bf16(m3, b3v, acc2[nb], 0, 0, 0);
    }

    // ---- epilogue: +b2, BN, ReLU, store ----
#pragma unroll
    for (int nb = 0; nb < 2; ++nb) {
        int col = wave * 32 + nb * 16 + fr;
        float bias = b2[col];
        float iv = gam[col] * rsqrtf(var[col] + BN_EPS);
        float mn = mean[col], bt = bet[col];
#pragma unroll
        for (int r = 0; r < 4; ++r) {
            int node = base + fg * 4 + r;
            float v = acc2[nb][r] + bias;
            v = (v - mn) * iv + bt;
            v = fmaxf(v, 0.f);
            if (last) fout[(size_t)node * DIM + col] = v;
            else hout[(size_t)node * DIM + col] = f2bf(v);
        }
    }
}

// ---------------- pooling: 8 blocks/graph non-atomic partials, then combine+divide ----------------
__global__ void __launch_bounds__(256) pool_partial_kernel(const float* __restrict__ h,
                                                           const int* __restrict__ batch,
                                                           float* __restrict__ partial)
{
    __shared__ float sums[256];
    __shared__ int sb[2];
    int g = blockIdx.x >> 3, split = blockIdx.x & 7;
    if (threadIdx.x < 2) {
        int target = g + threadIdx.x;
        int lo = 0, hi = N_NODES;
        while (lo < hi) { int mid = (lo + hi) >> 1; if (batch[mid] < target) lo = mid + 1; else hi = mid; }
        sb[threadIdx.x] = lo;
    }
    __syncthreads();
    int lo = sb[0], hi = sb[1];
    int d = threadIdx.x & 127, half = threadIdx.x >> 7;
    float acc = 0.f;
    for (int n = lo + split * 2 + half; n < hi; n += 16) acc += h[(size_t)n * DIM + d];
    sums[threadIdx.x] = acc;
    __syncthreads();
    if (threadIdx.x < 128)
        partial[blockIdx.x * DIM + threadIdx.x] = sums[threadIdx.x] + sums[threadIdx.x + 128];
}

__global__ void pool_comb_kernel(const float* __restrict__ partial,
                                 const int* __restrict__ batch,
                                 float* __restrict__ out)
{
    __shared__ int sb[2];
    int g = blockIdx.x, t = threadIdx.x;
    if (t < 2) {
        int target = g + t;
        int lo = 0, hi = N_NODES;
        while (lo < hi) { int mid = (lo + hi) >> 1; if (batch[mid] < target) lo = mid + 1; else hi = mid; }
        sb[t] = lo;
    }
    __syncthreads();
    float s = 0.f;
#pragma unroll
    for (int sp = 0; sp < 8; ++sp) s += partial[(g * 8 + sp) * DIM + t];
    float c = (float)(sb[1] - sb[0]);
    out[g * DIM + t] = s / fmaxf(c, 1.f);
}

extern "C" void kernel_launch(void* const* d_in, const int* in_sizes, int n_in,
                              void* d_out, int out_size, void* d_ws, size_t ws_size,
                              hipStream_t stream)
{
    const int*   feat_id = (const int*)d_in[0];
    const int*   eidx    = (const int*)d_in[1];
    const int*   batch   = (const int*)d_in[2];
    const float* rwse    = (const float*)d_in[3];
    const int*   indeg   = (const int*)d_in[4];
    const float* value_W = (const float*)d_in[5];
    const float* value_b = (const float*)d_in[6];
    const float* rwse_W  = (const float*)d_in[7];
    const float* rwse_b  = (const float*)d_in[8];
    const float* deg_emb = (const float*)d_in[9];
    const float* W1      = (const float*)d_in[10];
    const float* b1      = (const float*)d_in[11];
    const float* W2      = (const float*)d_in[12];
    const float* b2      = (const float*)d_in[13];
    const float* gam     = (const float*)d_in[14];
    const float* bet     = (const float*)d_in[15];
    const float* mean    = (const float*)d_in[16];
    const float* var     = (const float*)d_in[17];

    const int* srcv = eidx;
    const int* dstv = eidx + N_EDGES;

    char* p = (char*)d_ws;
    auto alloc = [&](size_t bytes) { char* r = p; p += (bytes + 255) & ~(size_t)255; return r; };
    unsigned short* hA   = (unsigned short*)alloc((size_t)N_NODES * DIM * 2);
    unsigned short* hB   = (unsigned short*)alloc((size_t)N_NODES * DIM * 2);
    int* cnt  = (int*)alloc((size_t)N_NODES * 4);
    int* rp   = (int*)alloc((size_t)(N_NODES + 1) * 4);
    int* cur  = (int*)alloc((size_t)N_NODES * 4);
    int* bsum = (int*)alloc(64 * 4);
    int* esrc = (int*)alloc((size_t)N_EDGES * 4);
    unsigned short* w1t = (unsigned short*)alloc((size_t)NLAYER * DIM * DIM * 2);
    unsigned short* w2t = (unsigned short*)alloc((size_t)NLAYER * DIM * DIM * 2);
    float* partial = (float*)alloc((size_t)NGRAPH * 8 * DIM * 4);

    float* out = (float*)d_out;
    float* hf  = out + NGRAPH * DIM;   // h output region [N, D] f32

    hipMemsetAsync(cnt, 0, (size_t)N_NODES * 4, stream);
    fused_pre_kernel<<<EN_BLOCKS + WT_BLOCKS + HB_BLOCKS, 256, 0, stream>>>(
        feat_id, rwse, indeg, value_W, value_b, rwse_W, rwse_b, deg_emb, hA,
        W1, W2, w1t, w2t, dstv, cnt);
    int nsb = (N_NODES + SCAN_BLK - 1) / SCAN_BLK;   // 49
    scanA_kernel<<<nsb, SCAN_BLK, 0, stream>>>(cnt, rp, bsum);
    scan_fixup_kernel<<<(N_NODES + 1 + 255) / 256, 256, 0, stream>>>(rp, bsum, cur, nsb);
    scatter_kernel<<<(N_EDGES + 255) / 256, 256, 0, stream>>>(srcv, dstv, cur, esrc);

    const int nlb = N_NODES / 16;   // 3125, exact
    for (int l = 0; l < NLAYER; ++l) {
        const unsigned short* hi = (l & 1) ? hB : hA;
        unsigned short*       ho = (l & 1) ? hA : hB;
        layer_kernel<<<nlb, 256, 0, stream>>>(hi, rp, esrc,
            w1t + l * DIM * DIM, w2t + l * DIM * DIM,
            b1 + l * DIM, b2 + l * DIM, gam + l * DIM, bet + l * DIM,
            mean + l * DIM, var + l * DIM,
            ho, hf, (l == NLAYER - 1) ? 1 : 0);
    }
    pool_partial_kernel<<<NGRAPH * 8, 256, 0, stream>>>(hf, batch, partial);
    pool_comb_kernel<<<NGRAPH, DIM, 0, stream>>>(partial, batch, out);
}